// Round 3
// baseline (550.980 us; speedup 1.0000x reference)
//
#include <hip/hip_runtime.h>
#include <hip/hip_bf16.h>

#define B_ 4
#define S_ 1024
#define D_ 256
#define H_ 8
#define LRELU_ALPHA 0.2f
#define MAXDEG 128

// ---------------- CSR build: one block per (b,i) row ----------------
__global__ __launch_bounds__(1024) void k_csr(const float* __restrict__ adj,
        int* __restrict__ nbr, int* __restrict__ cnt) {
    int row = blockIdx.x;            // b*S + i
    int j = threadIdx.x;
    __shared__ int c;
    if (j == 0) c = 0;
    __syncthreads();
    float a = adj[(size_t)row * S_ + j];
    if (a > 0.f) {
        int s = atomicAdd(&c, 1);
        if (s < MAXDEG) nbr[row * MAXDEG + s] = j;
    }
    __syncthreads();
    if (j == 0) cnt[row] = c < MAXDEG ? c : MAXDEG;
}

// ---------------- elementwise ----------------
__global__ void k_add_elu(const float* __restrict__ G, const float* __restrict__ X,
                          float* __restrict__ Hout, int n) {
    int i = blockIdx.x * blockDim.x + threadIdx.x;
    if (i >= n) return;
    float x = G[i] + X[i];
    Hout[i] = x > 0.f ? x : (__expf(x) - 1.f);
}

__global__ void k_reduce_heads(const float* __restrict__ P, const float* __restrict__ H,
                               float* __restrict__ C, int n) {
    int i = blockIdx.x * blockDim.x + threadIdx.x;
    if (i >= n) return;
    int bs = i >> 8, d = i & 255;
    const float* p = P + (size_t)bs * (H_ * 256) + d;
    float s = 0.f;
#pragma unroll
    for (int h = 0; h < H_; ++h) s += p[h * 256];
    C[i] = H[i] + s * (1.f / H_);
}

__global__ __launch_bounds__(256) void k_layernorm(const float* __restrict__ X,
        const float* __restrict__ g, const float* __restrict__ bta,
        float* __restrict__ Y) {
    int row = blockIdx.x * 4 + (threadIdx.x >> 6);
    int lane = threadIdx.x & 63;
    const float4 v = ((const float4*)(X + (size_t)row * 256))[lane];
    float s = v.x + v.y + v.z + v.w;
    float q = v.x * v.x + v.y * v.y + v.z * v.z + v.w * v.w;
    for (int o = 32; o; o >>= 1) { s += __shfl_xor(s, o); q += __shfl_xor(q, o); }
    float mu = s * (1.f / 256.f);
    float var = q * (1.f / 256.f) - mu * mu;
    if (var < 0.f) var = 0.f;
    float rs = rsqrtf(var + 1e-5f);
    float4 gg = ((const float4*)g)[lane];
    float4 bb = ((const float4*)bta)[lane];
    float4 o;
    o.x = (v.x - mu) * rs * gg.x + bb.x;
    o.y = (v.y - mu) * rs * gg.y + bb.y;
    o.z = (v.z - mu) * rs * gg.z + bb.z;
    o.w = (v.w - mu) * rs * gg.w + bb.w;
    ((float4*)(Y + (size_t)row * 256))[lane] = o;
}

__global__ void k_bias_gelu(float* __restrict__ M, const float* __restrict__ b1,
                            int n, int colmask) {
    int i = blockIdx.x * blockDim.x + threadIdx.x;
    if (i >= n) return;
    float x = M[i] + b1[i & colmask];
    float t = tanhf(0.7978845608028654f * (x + 0.044715f * x * x * x));
    M[i] = 0.5f * x * (1.f + t);
}

__global__ void k_final(const float* __restrict__ HLN, const float* __restrict__ FF,
                        const float* __restrict__ b2, float* __restrict__ out, int n) {
    int i = blockIdx.x * blockDim.x + threadIdx.x;
    if (i >= n) return;
    out[i] = HLN[i] + FF[i] + b2[i & 255];
}

// ---------------- GEMM: C[M,N] = A[M,K] @ B[K,N], all fp32 ----------------
#define BM 64
#define BN 64
#define BK 16
__global__ __launch_bounds__(256) void k_gemm(const float* __restrict__ A,
        const float* __restrict__ Bw, float* __restrict__ C,
        int M, int N, int K) {
    __shared__ float As[BK][BM + 1];
    __shared__ float Bs[BK][BN];
    int tid = threadIdx.x;
    int bm = blockIdx.y * BM, bn = blockIdx.x * BN;
    int tx = tid & 15, ty = tid >> 4;
    float acc[4][4] = {};
    for (int k0 = 0; k0 < K; k0 += BK) {
        {
            int mi = tid >> 2, kq = (tid & 3) * 4;
            const float4 av = *(const float4*)(A + (size_t)(bm + mi) * K + k0 + kq);
            As[kq + 0][mi] = av.x; As[kq + 1][mi] = av.y;
            As[kq + 2][mi] = av.z; As[kq + 3][mi] = av.w;
        }
        {
            int ki = tid >> 4, nq = (tid & 15) * 4;
            const float4 bv = *(const float4*)(Bw + (size_t)(k0 + ki) * N + bn + nq);
            Bs[ki][nq + 0] = bv.x; Bs[ki][nq + 1] = bv.y;
            Bs[ki][nq + 2] = bv.z; Bs[ki][nq + 3] = bv.w;
        }
        __syncthreads();
#pragma unroll
        for (int kk = 0; kk < BK; ++kk) {
            float a0 = As[kk][ty * 4 + 0], a1 = As[kk][ty * 4 + 1];
            float a2 = As[kk][ty * 4 + 2], a3 = As[kk][ty * 4 + 3];
            float b0 = Bs[kk][tx * 4 + 0], b1 = Bs[kk][tx * 4 + 1];
            float b2 = Bs[kk][tx * 4 + 2], b3 = Bs[kk][tx * 4 + 3];
            acc[0][0] += a0 * b0; acc[0][1] += a0 * b1; acc[0][2] += a0 * b2; acc[0][3] += a0 * b3;
            acc[1][0] += a1 * b0; acc[1][1] += a1 * b1; acc[1][2] += a1 * b2; acc[1][3] += a1 * b3;
            acc[2][0] += a2 * b0; acc[2][1] += a2 * b1; acc[2][2] += a2 * b2; acc[2][3] += a2 * b3;
            acc[3][0] += a3 * b0; acc[3][1] += a3 * b1; acc[3][2] += a3 * b2; acc[3][3] += a3 * b3;
        }
        __syncthreads();
    }
#pragma unroll
    for (int i = 0; i < 4; ++i) {
        float4 o = make_float4(acc[i][0], acc[i][1], acc[i][2], acc[i][3]);
        *(float4*)(C + (size_t)(bm + ty * 4 + i) * N + bn + tx * 4) = o;
    }
}

// ---------------- scores: src/dst[bs,h] = dot(hp[bs,h,:], a[h,:]) ----------------
__global__ __launch_bounds__(256) void k_scores(const float* __restrict__ hp,
        const float* __restrict__ asrc, const float* __restrict__ adst,
        float* __restrict__ src, float* __restrict__ dst, int dh) {
    int w = blockIdx.x * 4 + (threadIdx.x >> 6);
    int lane = threadIdx.x & 63;
    int h = w & (H_ - 1);
    int bs = w >> 3;
    const float* v = hp + (size_t)bs * H_ * dh + (size_t)h * dh;
    float s = 0.f, d = 0.f;
    for (int k = lane; k < dh; k += 64) {
        float x = v[k];
        s += x * asrc[h * dh + k];
        d += x * adst[h * dh + k];
    }
    for (int o = 32; o; o >>= 1) { s += __shfl_xor(s, o); d += __shfl_xor(d, o); }
    if (lane == 0) { src[w] = s; dst[w] = d; }
}

// ---------------- attention layers 0/1 (dh=32, concat), CSR sparse ----------------
__global__ __launch_bounds__(256) void k_attn_small(const float* __restrict__ hp,
        const float* __restrict__ src, const float* __restrict__ dst,
        const int* __restrict__ nbr, const int* __restrict__ cnts,
        float* __restrict__ out) {
    int w = blockIdx.x * 4 + (threadIdx.x >> 6);
    int lane = threadIdx.x & 63;
    int h = w & (H_ - 1);
    int i = (w >> 3) & (S_ - 1);
    int b = w >> 13;
    int row = b * S_ + i;
    int cnt = cnts[row];
    const int* nb = nbr + row * MAXDEG;
    float si = src[row * H_ + h];

    // phase 1: online softmax over neighbors
    float m = -1e30f, s = 0.f;
    for (int n = lane; n < cnt; n += 64) {
        int j = nb[n];
        float e = si + dst[(b * S_ + j) * H_ + h];
        e = e > 0.f ? e : LRELU_ALPHA * e;
        float mn = fmaxf(m, e);
        s = s * __expf(m - mn) + __expf(e - mn);
        m = mn;
    }
    for (int o = 32; o; o >>= 1) {
        float mo = __shfl_xor(m, o), so = __shfl_xor(s, o);
        float mn = fmaxf(m, mo);
        s = s * __expf(m - mn) + so * __expf(mo - mn);
        m = mn;
    }
    float invZ = s > 0.f ? 1.f / s : 0.f;

    // phase 2: lane = (half, d); two neighbors in flight
    int d = lane & 31, half = lane >> 5;
    float acc = 0.f;
    const float* hpb = hp + (size_t)b * S_ * 256 + h * 32 + d;
    for (int n = half; n < cnt; n += 2) {
        int j = nb[n];
        float e = si + dst[(b * S_ + j) * H_ + h];
        e = e > 0.f ? e : LRELU_ALPHA * e;
        float wgt = __expf(e - m);
        acc += wgt * hpb[(size_t)j * 256];
    }
    acc += __shfl_xor(acc, 32);
    if (half == 0) out[(size_t)row * 256 + h * 32 + d] = acc * invZ;
}

// ---------------- attention layer 2 (dh=256), CSR sparse ----------------
__global__ __launch_bounds__(256) void k_attn_big(const float* __restrict__ hp2,
        const float* __restrict__ src2, const float* __restrict__ dst2,
        const int* __restrict__ nbr, const int* __restrict__ cnts,
        float* __restrict__ P) {
    int w = blockIdx.x * 4 + (threadIdx.x >> 6);
    int lane = threadIdx.x & 63;
    int h = w & (H_ - 1);
    int i = (w >> 3) & (S_ - 1);
    int b = w >> 13;
    int row = b * S_ + i;
    int cnt = cnts[row];
    const int* nb = nbr + row * MAXDEG;
    float si = src2[row * H_ + h];

    float m = -1e30f, s = 0.f;
    for (int n = lane; n < cnt; n += 64) {
        int j = nb[n];
        float e = si + dst2[(b * S_ + j) * H_ + h];
        e = e > 0.f ? e : LRELU_ALPHA * e;
        float mn = fmaxf(m, e);
        s = s * __expf(m - mn) + __expf(e - mn);
        m = mn;
    }
    for (int o = 32; o; o >>= 1) {
        float mo = __shfl_xor(m, o), so = __shfl_xor(s, o);
        float mn = fmaxf(m, mo);
        s = s * __expf(m - mn) + so * __expf(mo - mn);
        m = mn;
    }
    float invZ = s > 0.f ? 1.f / s : 0.f;

    // phase 2: each lane holds 4 of 256 dims; sweep neighbor list
    float4 acc = make_float4(0.f, 0.f, 0.f, 0.f);
    const float* base = hp2 + (size_t)b * S_ * 2048 + h * 256 + lane * 4;
    for (int n = 0; n < cnt; ++n) {
        int j = nb[n];
        float e = si + dst2[(b * S_ + j) * H_ + h];
        e = e > 0.f ? e : LRELU_ALPHA * e;
        float wgt = __expf(e - m);
        float4 v = *(const float4*)(base + (size_t)j * 2048);
        acc.x += wgt * v.x; acc.y += wgt * v.y;
        acc.z += wgt * v.z; acc.w += wgt * v.w;
    }
    float4 o = make_float4(acc.x * invZ, acc.y * invZ, acc.z * invZ, acc.w * invZ);
    *(float4*)(P + ((size_t)row * H_ + h) * 256 + lane * 4) = o;
}

extern "C" void kernel_launch(void* const* d_in, const int* in_sizes, int n_in,
                              void* d_out, int out_size, void* d_ws, size_t ws_size,
                              hipStream_t stream) {
    const float* adj   = (const float*)d_in[0];
    const float* x     = (const float*)d_in[1];
    const float* W0    = (const float*)d_in[2];
    const float* as0   = (const float*)d_in[3];
    const float* ad0   = (const float*)d_in[4];
    const float* W1    = (const float*)d_in[5];
    const float* as1   = (const float*)d_in[6];
    const float* ad1   = (const float*)d_in[7];
    const float* W2    = (const float*)d_in[8];
    const float* as2   = (const float*)d_in[9];
    const float* ad2   = (const float*)d_in[10];
    const float* ln_g  = (const float*)d_in[11];
    const float* ln_b  = (const float*)d_in[12];
    const float* ff_w1 = (const float*)d_in[13];
    const float* ff_b1 = (const float*)d_in[14];
    const float* ff_w2 = (const float*)d_in[15];
    const float* ff_b2 = (const float*)d_in[16];

    float* ws = (float*)d_ws;
    const size_t NTOK = (size_t)B_ * S_ * D_;        // 1048576
    float* H   = ws;                  // [4096,256]
    float* HP  = ws + 1048576;        // [4096,256]
    float* G   = ws + 2097152;        // [4096,256]
    float* SRC = ws + 3145728;        // [4096,8]
    float* DST = ws + 3178496;        // [4096,8]
    float* E   = ws + 3211264;        // HP2 [4096,2048]; later HLN/MID/FF alias
    float* P   = ws + 11599872;       // [4096,8,256]
    int*   NBR = (int*)(ws + 19988480);   // [4096,128]
    int*   CNT = (int*)(ws + 20512768);   // [4096]
    float* HLN = E;
    float* MID = E + 1048576;
    float* FF  = E + 3145728;

    // adjacency -> CSR (rebuilt every call; ws is re-poisoned by harness)
    k_csr<<<4096, 1024, 0, stream>>>(adj, NBR, CNT);

    // ---- GAT layer 0 (input = x directly) ----
    k_gemm<<<dim3(256 / BN, 4096 / BM), 256, 0, stream>>>(x, W0, HP, 4096, 256, 256);
    k_scores<<<8192, 256, 0, stream>>>(HP, as0, ad0, SRC, DST, 32);
    k_attn_small<<<8192, 256, 0, stream>>>(HP, SRC, DST, NBR, CNT, G);
    k_add_elu<<<4096, 256, 0, stream>>>(G, x, H, (int)NTOK);

    // ---- GAT layer 1 ----
    k_gemm<<<dim3(256 / BN, 4096 / BM), 256, 0, stream>>>(H, W1, HP, 4096, 256, 256);
    k_scores<<<8192, 256, 0, stream>>>(HP, as1, ad1, SRC, DST, 32);
    k_attn_small<<<8192, 256, 0, stream>>>(HP, SRC, DST, NBR, CNT, G);
    k_add_elu<<<4096, 256, 0, stream>>>(G, H, H, (int)NTOK);

    // ---- GAT layer 2 (mean over heads) ----
    k_gemm<<<dim3(2048 / BN, 4096 / BM), 256, 0, stream>>>(H, W2, E, 4096, 2048, 256);
    k_scores<<<8192, 256, 0, stream>>>(E, as2, ad2, SRC, DST, 256);
    k_attn_big<<<8192, 256, 0, stream>>>(E, SRC, DST, NBR, CNT, P);
    k_reduce_heads<<<4096, 256, 0, stream>>>(P, H, G, (int)NTOK);   // G = h post-layer2

    // ---- LayerNorm ----
    k_layernorm<<<1024, 256, 0, stream>>>(G, ln_g, ln_b, HLN);

    // ---- FFN ----
    k_gemm<<<dim3(512 / BN, 4096 / BM), 256, 0, stream>>>(HLN, ff_w1, MID, 4096, 512, 256);
    k_bias_gelu<<<8192, 256, 0, stream>>>(MID, ff_b1, 2097152, 511);
    k_gemm<<<dim3(256 / BN, 4096 / BM), 256, 0, stream>>>(MID, ff_w2, FF, 4096, 256, 512);
    k_final<<<4096, 256, 0, stream>>>(HLN, FF, ff_b2, (float*)d_out, (int)NTOK);
}

// Round 4
// 468.987 us; speedup vs baseline: 1.1748x; 1.1748x over previous
//
#include <hip/hip_runtime.h>
#include <hip/hip_bf16.h>

#define B_ 4
#define S_ 1024
#define D_ 256
#define H_ 8
#define LRELU_ALPHA 0.2f
#define MAXDEG 128

// ---------------- CSR build: one block per (b,i) row ----------------
__global__ __launch_bounds__(1024) void k_csr(const float* __restrict__ adj,
        int* __restrict__ nbr, int* __restrict__ cnt) {
    int row = blockIdx.x;            // b*S + i
    int j = threadIdx.x;
    __shared__ int c;
    if (j == 0) c = 0;
    __syncthreads();
    float a = adj[(size_t)row * S_ + j];
    if (a > 0.f) {
        int s = atomicAdd(&c, 1);
        if (s < MAXDEG) nbr[row * MAXDEG + s] = j;
    }
    __syncthreads();
    if (j == 0) cnt[row] = c < MAXDEG ? c : MAXDEG;
}

// ---------------- GEMM: C[M,N] = A[M,K] @ B[K,N], all fp32 ----------------
#define BM 64
#define BN 64
#define BK 16
__global__ __launch_bounds__(256) void k_gemm(const float* __restrict__ A,
        const float* __restrict__ Bw, float* __restrict__ C,
        int M, int N, int K) {
    __shared__ float As[BK][BM + 1];
    __shared__ float Bs[BK][BN];
    int tid = threadIdx.x;
    int bm = blockIdx.y * BM, bn = blockIdx.x * BN;
    int tx = tid & 15, ty = tid >> 4;
    float acc[4][4] = {};
    for (int k0 = 0; k0 < K; k0 += BK) {
        {
            int mi = tid >> 2, kq = (tid & 3) * 4;
            const float4 av = *(const float4*)(A + (size_t)(bm + mi) * K + k0 + kq);
            As[kq + 0][mi] = av.x; As[kq + 1][mi] = av.y;
            As[kq + 2][mi] = av.z; As[kq + 3][mi] = av.w;
        }
        {
            int ki = tid >> 4, nq = (tid & 15) * 4;
            const float4 bv = *(const float4*)(Bw + (size_t)(k0 + ki) * N + bn + nq);
            Bs[ki][nq + 0] = bv.x; Bs[ki][nq + 1] = bv.y;
            Bs[ki][nq + 2] = bv.z; Bs[ki][nq + 3] = bv.w;
        }
        __syncthreads();
#pragma unroll
        for (int kk = 0; kk < BK; ++kk) {
            float a0 = As[kk][ty * 4 + 0], a1 = As[kk][ty * 4 + 1];
            float a2 = As[kk][ty * 4 + 2], a3 = As[kk][ty * 4 + 3];
            float b0 = Bs[kk][tx * 4 + 0], b1 = Bs[kk][tx * 4 + 1];
            float b2 = Bs[kk][tx * 4 + 2], b3 = Bs[kk][tx * 4 + 3];
            acc[0][0] += a0 * b0; acc[0][1] += a0 * b1; acc[0][2] += a0 * b2; acc[0][3] += a0 * b3;
            acc[1][0] += a1 * b0; acc[1][1] += a1 * b1; acc[1][2] += a1 * b2; acc[1][3] += a1 * b3;
            acc[2][0] += a2 * b0; acc[2][1] += a2 * b1; acc[2][2] += a2 * b2; acc[2][3] += a2 * b3;
            acc[3][0] += a3 * b0; acc[3][1] += a3 * b1; acc[3][2] += a3 * b2; acc[3][3] += a3 * b3;
        }
        __syncthreads();
    }
#pragma unroll
    for (int i = 0; i < 4; ++i) {
        float4 o = make_float4(acc[i][0], acc[i][1], acc[i][2], acc[i][3]);
        *(float4*)(C + (size_t)(bm + ty * 4 + i) * N + bn + tx * 4) = o;
    }
}

// ---------------- scores: src/dst[bs,h] = dot(hp[bs,h,:], a[h,:]) ----------------
__global__ __launch_bounds__(256) void k_scores(const float* __restrict__ hp,
        const float* __restrict__ asrc, const float* __restrict__ adst,
        float* __restrict__ src, float* __restrict__ dst, int dh) {
    int w = blockIdx.x * 4 + (threadIdx.x >> 6);
    int lane = threadIdx.x & 63;
    int h = w & (H_ - 1);
    int bs = w >> 3;
    const float* v = hp + (size_t)bs * H_ * dh + (size_t)h * dh;
    float s = 0.f, d = 0.f;
    for (int k = lane; k < dh; k += 64) {
        float x = v[k];
        s += x * asrc[h * dh + k];
        d += x * adst[h * dh + k];
    }
    for (int o = 32; o; o >>= 1) { s += __shfl_xor(s, o); d += __shfl_xor(d, o); }
    if (lane == 0) { src[w] = s; dst[w] = d; }
}

// ------- attention layers 0/1 fused: block per row, all heads; out = elu(agg + X) -------
__global__ __launch_bounds__(256) void k_attn_small_f(const float* __restrict__ hp,
        const float* __restrict__ src, const float* __restrict__ dst,
        const int* __restrict__ nbr, const int* __restrict__ cnts,
        const float* __restrict__ X, float* __restrict__ Hout) {
    int row = blockIdx.x;                 // b*S + i
    int tid = threadIdx.x;
    int rb = row & ~(S_ - 1);             // b*S
    __shared__ int nb[MAXDEG];
    __shared__ float ss[8];
    __shared__ float ew[MAXDEG * 9];      // [n][h] pitch 9 (bank-conflict-free)
    int cnt = cnts[row];
    for (int t = tid; t < cnt; t += 256) nb[t] = nbr[row * MAXDEG + t];
    if (tid < 8) ss[tid] = src[row * H_ + tid];
    __syncthreads();
    // raw scores e[n][h]
    for (int idx = tid; idx < cnt * 8; idx += 256) {
        int n = idx >> 3, h = idx & 7;
        int j = nb[n];
        float e = ss[h] + dst[(rb + j) * H_ + h];
        ew[n * 9 + h] = e > 0.f ? e : LRELU_ALPHA * e;
    }
    __syncthreads();
    // per-head softmax: half-wave (32 lanes) owns one head
    {
        int lane = tid & 63, wv = tid >> 6;
        int h = wv * 2 + (lane >> 5), sub = lane & 31;
        float m = -1e30f;
        for (int n = sub; n < cnt; n += 32) m = fmaxf(m, ew[n * 9 + h]);
        for (int o = 16; o; o >>= 1) m = fmaxf(m, __shfl_xor(m, o));
        float s = 0.f;
        for (int n = sub; n < cnt; n += 32) {
            float v = __expf(ew[n * 9 + h] - m); ew[n * 9 + h] = v; s += v;
        }
        for (int o = 16; o; o >>= 1) s += __shfl_xor(s, o);
        float inv = s > 0.f ? 1.f / s : 0.f;
        for (int n = sub; n < cnt; n += 32) ew[n * 9 + h] *= inv;
    }
    __syncthreads();
    // aggregate: thread t owns dim t (head t>>5); coalesced 1 KB row reads
    int h = tid >> 5;
    float acc = 0.f;
    const float* hpb = hp + (size_t)rb * 256;
    for (int n = 0; n < cnt; ++n) {
        int j = nb[n];
        acc += ew[n * 9 + h] * hpb[(size_t)j * 256 + tid];
    }
    float o = acc + X[(size_t)row * 256 + tid];
    Hout[(size_t)row * 256 + tid] = o > 0.f ? o : (__expf(o) - 1.f);
}

// ------- layer 2 fused: block per row; head-mean + residual + LayerNorm epilogue -------
__global__ __launch_bounds__(256) void k_attn_big_f(const float* __restrict__ hp2,
        const float* __restrict__ src2, const float* __restrict__ dst2,
        const int* __restrict__ nbr, const int* __restrict__ cnts,
        const float* __restrict__ Hres, const float* __restrict__ g,
        const float* __restrict__ bta, float* __restrict__ HLN) {
    int row = blockIdx.x;
    int tid = threadIdx.x;
    int rb = row & ~(S_ - 1);
    __shared__ int nb[MAXDEG];
    __shared__ float ss[8];
    __shared__ float ew[MAXDEG * 9];
    __shared__ float red[256 * 4];
    int cnt = cnts[row];
    for (int t = tid; t < cnt; t += 256) nb[t] = nbr[row * MAXDEG + t];
    if (tid < 8) ss[tid] = src2[row * H_ + tid];
    __syncthreads();
    for (int idx = tid; idx < cnt * 8; idx += 256) {
        int n = idx >> 3, h = idx & 7;
        int j = nb[n];
        float e = ss[h] + dst2[(rb + j) * H_ + h];
        ew[n * 9 + h] = e > 0.f ? e : LRELU_ALPHA * e;
    }
    __syncthreads();
    {
        int lane = tid & 63, wv = tid >> 6;
        int h = wv * 2 + (lane >> 5), sub = lane & 31;
        float m = -1e30f;
        for (int n = sub; n < cnt; n += 32) m = fmaxf(m, ew[n * 9 + h]);
        for (int o = 16; o; o >>= 1) m = fmaxf(m, __shfl_xor(m, o));
        float s = 0.f;
        for (int n = sub; n < cnt; n += 32) {
            float v = __expf(ew[n * 9 + h] - m); ew[n * 9 + h] = v; s += v;
        }
        for (int o = 16; o; o >>= 1) s += __shfl_xor(s, o);
        float inv = s > 0.f ? 0.125f / s : 0.f;     // fold in 1/H head-mean
        for (int n = sub; n < cnt; n += 32) ew[n * 9 + h] *= inv;
    }
    __syncthreads();
    // aggregate: thread t -> heads (t>>6, t>>6+4), dims d0..d0+3; full 8KB row coalesced
    int h0 = tid >> 6;
    int d0 = (tid * 4) & 255;
    float4 acc = make_float4(0.f, 0.f, 0.f, 0.f);
    for (int n = 0; n < cnt; ++n) {
        int j = nb[n];
        const float* r = hp2 + (size_t)(rb + j) * 2048;
        float w0 = ew[n * 9 + h0], w1 = ew[n * 9 + h0 + 4];
        float4 v0 = *(const float4*)(r + h0 * 256 + d0);
        float4 v1 = *(const float4*)(r + (h0 + 4) * 256 + d0);
        acc.x += w0 * v0.x + w1 * v1.x;
        acc.y += w0 * v0.y + w1 * v1.y;
        acc.z += w0 * v0.z + w1 * v1.z;
        acc.w += w0 * v0.w + w1 * v1.w;
    }
    ((float4*)red)[tid] = acc;
    __syncthreads();
    if (tid < 64) {   // wave0 holds the whole 256-dim row: reduce groups + residual + LN
        float4 a = ((const float4*)red)[tid];
        float4 b4 = ((const float4*)red)[tid + 64];
        float4 c4 = ((const float4*)red)[tid + 128];
        float4 dd = ((const float4*)red)[tid + 192];
        float4 hres = ((const float4*)(Hres + (size_t)row * 256))[tid];
        float4 v;
        v.x = hres.x + a.x + b4.x + c4.x + dd.x;
        v.y = hres.y + a.y + b4.y + c4.y + dd.y;
        v.z = hres.z + a.z + b4.z + c4.z + dd.z;
        v.w = hres.w + a.w + b4.w + c4.w + dd.w;
        float s = v.x + v.y + v.z + v.w;
        float q = v.x * v.x + v.y * v.y + v.z * v.z + v.w * v.w;
        for (int o = 32; o; o >>= 1) { s += __shfl_xor(s, o); q += __shfl_xor(q, o); }
        float mu = s * (1.f / 256.f);
        float var = q * (1.f / 256.f) - mu * mu;
        if (var < 0.f) var = 0.f;
        float rs = rsqrtf(var + 1e-5f);
        float4 gg = ((const float4*)g)[tid];
        float4 bb = ((const float4*)bta)[tid];
        float4 o;
        o.x = (v.x - mu) * rs * gg.x + bb.x;
        o.y = (v.y - mu) * rs * gg.y + bb.y;
        o.z = (v.z - mu) * rs * gg.z + bb.z;
        o.w = (v.w - mu) * rs * gg.w + bb.w;
        ((float4*)(HLN + (size_t)row * 256))[tid] = o;
    }
}

__global__ void k_bias_gelu(float* __restrict__ M, const float* __restrict__ b1,
                            int n, int colmask) {
    int i = blockIdx.x * blockDim.x + threadIdx.x;
    if (i >= n) return;
    float x = M[i] + b1[i & colmask];
    float t = tanhf(0.7978845608028654f * (x + 0.044715f * x * x * x));
    M[i] = 0.5f * x * (1.f + t);
}

__global__ void k_final(const float* __restrict__ HLN, const float* __restrict__ FF,
                        const float* __restrict__ b2, float* __restrict__ out, int n) {
    int i = blockIdx.x * blockDim.x + threadIdx.x;
    if (i >= n) return;
    out[i] = HLN[i] + FF[i] + b2[i & 255];
}

extern "C" void kernel_launch(void* const* d_in, const int* in_sizes, int n_in,
                              void* d_out, int out_size, void* d_ws, size_t ws_size,
                              hipStream_t stream) {
    const float* adj   = (const float*)d_in[0];
    const float* x     = (const float*)d_in[1];
    const float* W0    = (const float*)d_in[2];
    const float* as0   = (const float*)d_in[3];
    const float* ad0   = (const float*)d_in[4];
    const float* W1    = (const float*)d_in[5];
    const float* as1   = (const float*)d_in[6];
    const float* ad1   = (const float*)d_in[7];
    const float* W2    = (const float*)d_in[8];
    const float* as2   = (const float*)d_in[9];
    const float* ad2   = (const float*)d_in[10];
    const float* ln_g  = (const float*)d_in[11];
    const float* ln_b  = (const float*)d_in[12];
    const float* ff_w1 = (const float*)d_in[13];
    const float* ff_b1 = (const float*)d_in[14];
    const float* ff_w2 = (const float*)d_in[15];
    const float* ff_b2 = (const float*)d_in[16];

    float* ws = (float*)d_ws;
    float* H   = ws;                  // [4096,256]
    float* HP  = ws + 1048576;        // [4096,256]
    float* HLN = ws + 2097152;        // [4096,256] (old G slot — must NOT alias E)
    float* SRC = ws + 3145728;        // [4096,8]
    float* DST = ws + 3178496;        // [4096,8]
    float* E   = ws + 3211264;        // HP2 [4096,2048]; later MID/FF alias
    int*   NBR = (int*)(ws + 19988480);   // [4096,128]
    int*   CNT = (int*)(ws + 20512768);   // [4096]
    float* MID = E + 1048576;         // [4096,512] (E region free after attn_big)
    float* FF  = E + 3145728;         // [4096,256]

    k_csr<<<4096, 1024, 0, stream>>>(adj, NBR, CNT);

    // ---- GAT layer 0 ----
    k_gemm<<<dim3(256 / BN, 4096 / BM), 256, 0, stream>>>(x, W0, HP, 4096, 256, 256);
    k_scores<<<8192, 256, 0, stream>>>(HP, as0, ad0, SRC, DST, 32);
    k_attn_small_f<<<4096, 256, 0, stream>>>(HP, SRC, DST, NBR, CNT, x, H);

    // ---- GAT layer 1 ----
    k_gemm<<<dim3(256 / BN, 4096 / BM), 256, 0, stream>>>(H, W1, HP, 4096, 256, 256);
    k_scores<<<8192, 256, 0, stream>>>(HP, as1, ad1, SRC, DST, 32);
    k_attn_small_f<<<4096, 256, 0, stream>>>(HP, SRC, DST, NBR, CNT, H, H);

    // ---- GAT layer 2 + head-mean + residual + LayerNorm ----
    k_gemm<<<dim3(2048 / BN, 4096 / BM), 256, 0, stream>>>(H, W2, E, 4096, 2048, 256);
    k_scores<<<8192, 256, 0, stream>>>(E, as2, ad2, SRC, DST, 256);
    k_attn_big_f<<<4096, 256, 0, stream>>>(E, SRC, DST, NBR, CNT, H, ln_g, ln_b, HLN);

    // ---- FFN ----
    k_gemm<<<dim3(512 / BN, 4096 / BM), 256, 0, stream>>>(HLN, ff_w1, MID, 4096, 512, 256);
    k_bias_gelu<<<8192, 256, 0, stream>>>(MID, ff_b1, 2097152, 511);
    k_gemm<<<dim3(256 / BN, 4096 / BM), 256, 0, stream>>>(MID, ff_w2, FF, 4096, 256, 512);
    k_final<<<4096, 256, 0, stream>>>(HLN, FF, ff_b2, (float*)d_out, 1048576);
}

// Round 5
// 288.182 us; speedup vs baseline: 1.9119x; 1.6274x over previous
//
#include <hip/hip_runtime.h>
#include <hip/hip_bf16.h>

#define B_ 4
#define S_ 1024
#define D_ 256
#define H_ 8
#define LRELU_ALPHA 0.2f
#define MAXDEG 128

typedef __attribute__((ext_vector_type(8))) short short8;
typedef __attribute__((ext_vector_type(4))) float floatx4;

__device__ __forceinline__ float bf2f(unsigned short u) {
    union { unsigned int i; float f; } c; c.i = ((unsigned int)u) << 16; return c.f;
}
__device__ __forceinline__ unsigned short f2bf(float f) {
    union { float f; unsigned int u; } c; c.f = f;
    unsigned int r = (c.u + 0x7FFF + ((c.u >> 16) & 1)) >> 16;
    return (unsigned short)r;
}

// ---------------- CSR build ----------------
__global__ __launch_bounds__(1024) void k_csr(const float* __restrict__ adj,
        int* __restrict__ nbr, int* __restrict__ cnt) {
    int row = blockIdx.x;
    int j = threadIdx.x;
    __shared__ int c;
    if (j == 0) c = 0;
    __syncthreads();
    float a = adj[(size_t)row * S_ + j];
    if (a > 0.f) {
        int s = atomicAdd(&c, 1);
        if (s < MAXDEG) nbr[row * MAXDEG + s] = j;
    }
    __syncthreads();
    if (j == 0) cnt[row] = c < MAXDEG ? c : MAXDEG;
}

// ---------------- fp32 -> bf16 elementwise (x input) ----------------
__global__ void k_cast4(const float* __restrict__ x, unsigned short* __restrict__ o, int n4) {
    int i = blockIdx.x * blockDim.x + threadIdx.x;
    if (i >= n4) return;
    float4 v = ((const float4*)x)[i];
    ushort4 u; u.x = f2bf(v.x); u.y = f2bf(v.y); u.z = f2bf(v.z); u.w = f2bf(v.w);
    ((ushort4*)o)[i] = u;
}

// ---------------- W[K][N] fp32 -> Bt[N][K] bf16 (tiled transpose) ----------------
__global__ __launch_bounds__(256) void k_castT(const float* __restrict__ W,
        unsigned short* __restrict__ out, int K, int N) {
    __shared__ float t[32][33];
    int k0 = blockIdx.x * 32, n0 = blockIdx.y * 32;
    int tx = threadIdx.x & 31, ty = threadIdx.x >> 5;
#pragma unroll
    for (int i = 0; i < 4; ++i)
        t[ty + 8 * i][tx] = W[(size_t)(k0 + ty + 8 * i) * N + n0 + tx];
    __syncthreads();
#pragma unroll
    for (int i = 0; i < 4; ++i)
        out[(size_t)(n0 + ty + 8 * i) * K + k0 + tx] = f2bf(t[tx][ty + 8 * i]);
}

// ---------------- MFMA GEMM: C[M,N] = A[M,K]bf16 @ Bt[N,K]bf16 ----------------
// 64x64 tile, 4 waves (2x2), mfma_f32_16x16x32_bf16.
// LDS pitch 40 ushorts (80B = 20 banks): b128 frag reads <=2-way conflicts.
__global__ __launch_bounds__(256) void k_gemm_mfma(const unsigned short* __restrict__ A,
        const unsigned short* __restrict__ Bt, void* __restrict__ Cout,
        int M, int N, int K, int bf16out) {
    __shared__ unsigned short As[64][40];
    __shared__ unsigned short Bs[64][40];
    int tid = threadIdx.x;
    int bm = blockIdx.y * 64, bn = blockIdx.x * 64;
    int lane = tid & 63, wv = tid >> 6;
    int wm = (wv & 1) * 32, wn = (wv >> 1) * 32;
    int lrow = lane & 15, lq = lane >> 4;
    floatx4 acc00 = {0.f,0.f,0.f,0.f}, acc01 = acc00, acc10 = acc00, acc11 = acc00;
    int sm = tid >> 2, skq = (tid & 3) * 8;
    for (int k0 = 0; k0 < K; k0 += 32) {
        *(short8*)&As[sm][skq] = *(const short8*)(A + (size_t)(bm + sm) * K + k0 + skq);
        *(short8*)&Bs[sm][skq] = *(const short8*)(Bt + (size_t)(bn + sm) * K + k0 + skq);
        __syncthreads();
        short8 a0 = *(const short8*)&As[wm + lrow][lq * 8];
        short8 a1 = *(const short8*)&As[wm + 16 + lrow][lq * 8];
        short8 b0 = *(const short8*)&Bs[wn + lrow][lq * 8];
        short8 b1 = *(const short8*)&Bs[wn + 16 + lrow][lq * 8];
        acc00 = __builtin_amdgcn_mfma_f32_16x16x32_bf16(a0, b0, acc00, 0, 0, 0);
        acc01 = __builtin_amdgcn_mfma_f32_16x16x32_bf16(a0, b1, acc01, 0, 0, 0);
        acc10 = __builtin_amdgcn_mfma_f32_16x16x32_bf16(a1, b0, acc10, 0, 0, 0);
        acc11 = __builtin_amdgcn_mfma_f32_16x16x32_bf16(a1, b1, acc11, 0, 0, 0);
        __syncthreads();
    }
    // C/D layout: col = lane&15, row = (lane>>4)*4 + r  [m89/m91 verified]
#pragma unroll
    for (int mi = 0; mi < 2; ++mi)
#pragma unroll
        for (int ni = 0; ni < 2; ++ni) {
            floatx4 a = mi == 0 ? (ni == 0 ? acc00 : acc01) : (ni == 0 ? acc10 : acc11);
#pragma unroll
            for (int r = 0; r < 4; ++r) {
                int grow = bm + wm + mi * 16 + lq * 4 + r;
                int gcol = bn + wn + ni * 16 + lrow;
                if (bf16out) ((unsigned short*)Cout)[(size_t)grow * N + gcol] = f2bf(a[r]);
                else         ((float*)Cout)[(size_t)grow * N + gcol] = a[r];
            }
        }
}

// ---------------- scores from bf16 hp ----------------
__global__ __launch_bounds__(256) void k_scores(const unsigned short* __restrict__ hp,
        const float* __restrict__ asrc, const float* __restrict__ adst,
        float* __restrict__ src, float* __restrict__ dst, int dh) {
    int w = blockIdx.x * 4 + (threadIdx.x >> 6);
    int lane = threadIdx.x & 63;
    int h = w & (H_ - 1);
    int bs = w >> 3;
    const unsigned short* v = hp + (size_t)bs * H_ * dh + (size_t)h * dh;
    float s = 0.f, d = 0.f;
    for (int k = lane; k < dh; k += 64) {
        float x = bf2f(v[k]);
        s += x * asrc[h * dh + k];
        d += x * adst[h * dh + k];
    }
    for (int o = 32; o; o >>= 1) { s += __shfl_xor(s, o); d += __shfl_xor(d, o); }
    if (lane == 0) { src[w] = s; dst[w] = d; }
}

// ------- attn layers 0/1 fused (bf16 hp): out = elu(agg + X), fp32 + bf16 copies -------
__global__ __launch_bounds__(256) void k_attn_small_f(const unsigned short* __restrict__ hp,
        const float* __restrict__ src, const float* __restrict__ dst,
        const int* __restrict__ nbr, const int* __restrict__ cnts,
        const float* __restrict__ X, float* __restrict__ Hout,
        unsigned short* __restrict__ Hb) {
    int row = blockIdx.x;
    int tid = threadIdx.x;
    int rb = row & ~(S_ - 1);
    __shared__ int nb[MAXDEG];
    __shared__ float ss[8];
    __shared__ float ew[MAXDEG * 9];
    int cnt = cnts[row];
    for (int t = tid; t < cnt; t += 256) nb[t] = nbr[row * MAXDEG + t];
    if (tid < 8) ss[tid] = src[row * H_ + tid];
    __syncthreads();
    for (int idx = tid; idx < cnt * 8; idx += 256) {
        int n = idx >> 3, h = idx & 7;
        int j = nb[n];
        float e = ss[h] + dst[(rb + j) * H_ + h];
        ew[n * 9 + h] = e > 0.f ? e : LRELU_ALPHA * e;
    }
    __syncthreads();
    {
        int lane = tid & 63, wv = tid >> 6;
        int h = wv * 2 + (lane >> 5), sub = lane & 31;
        float m = -1e30f;
        for (int n = sub; n < cnt; n += 32) m = fmaxf(m, ew[n * 9 + h]);
        for (int o = 16; o; o >>= 1) m = fmaxf(m, __shfl_xor(m, o));
        float s = 0.f;
        for (int n = sub; n < cnt; n += 32) {
            float v = __expf(ew[n * 9 + h] - m); ew[n * 9 + h] = v; s += v;
        }
        for (int o = 16; o; o >>= 1) s += __shfl_xor(s, o);
        float inv = s > 0.f ? 1.f / s : 0.f;
        for (int n = sub; n < cnt; n += 32) ew[n * 9 + h] *= inv;
    }
    __syncthreads();
    int h = tid >> 5;
    float acc = 0.f;
    const unsigned short* hpb = hp + (size_t)rb * 256;
    for (int n = 0; n < cnt; ++n) {
        int j = nb[n];
        acc += ew[n * 9 + h] * bf2f(hpb[(size_t)j * 256 + tid]);
    }
    float o = acc + X[(size_t)row * 256 + tid];
    o = o > 0.f ? o : (__expf(o) - 1.f);
    Hout[(size_t)row * 256 + tid] = o;
    Hb[(size_t)row * 256 + tid] = f2bf(o);
}

// ------- layer 2 fused (bf16 hp2): head-mean + residual + LayerNorm; fp32+bf16 out -------
__global__ __launch_bounds__(256) void k_attn_big_f(const unsigned short* __restrict__ hp2,
        const float* __restrict__ src2, const float* __restrict__ dst2,
        const int* __restrict__ nbr, const int* __restrict__ cnts,
        const float* __restrict__ Hres, const float* __restrict__ g,
        const float* __restrict__ bta, float* __restrict__ HLN,
        unsigned short* __restrict__ HLNb) {
    int row = blockIdx.x;
    int tid = threadIdx.x;
    int rb = row & ~(S_ - 1);
    __shared__ int nb[MAXDEG];
    __shared__ float ss[8];
    __shared__ float ew[MAXDEG * 9];
    __shared__ float red[256 * 4];
    int cnt = cnts[row];
    for (int t = tid; t < cnt; t += 256) nb[t] = nbr[row * MAXDEG + t];
    if (tid < 8) ss[tid] = src2[row * H_ + tid];
    __syncthreads();
    for (int idx = tid; idx < cnt * 8; idx += 256) {
        int n = idx >> 3, h = idx & 7;
        int j = nb[n];
        float e = ss[h] + dst2[(rb + j) * H_ + h];
        ew[n * 9 + h] = e > 0.f ? e : LRELU_ALPHA * e;
    }
    __syncthreads();
    {
        int lane = tid & 63, wv = tid >> 6;
        int h = wv * 2 + (lane >> 5), sub = lane & 31;
        float m = -1e30f;
        for (int n = sub; n < cnt; n += 32) m = fmaxf(m, ew[n * 9 + h]);
        for (int o = 16; o; o >>= 1) m = fmaxf(m, __shfl_xor(m, o));
        float s = 0.f;
        for (int n = sub; n < cnt; n += 32) {
            float v = __expf(ew[n * 9 + h] - m); ew[n * 9 + h] = v; s += v;
        }
        for (int o = 16; o; o >>= 1) s += __shfl_xor(s, o);
        float inv = s > 0.f ? 0.125f / s : 0.f;
        for (int n = sub; n < cnt; n += 32) ew[n * 9 + h] *= inv;
    }
    __syncthreads();
    int h0 = tid >> 6;
    int d0 = (tid * 4) & 255;
    float4 acc = make_float4(0.f, 0.f, 0.f, 0.f);
    for (int n = 0; n < cnt; ++n) {
        int j = nb[n];
        const unsigned short* r = hp2 + (size_t)(rb + j) * 2048 + h0 * 256 + d0;
        float w0 = ew[n * 9 + h0], w1 = ew[n * 9 + h0 + 4];
        ushort4 u0 = *(const ushort4*)r;
        ushort4 u1 = *(const ushort4*)(r + 1024);
        acc.x += w0 * bf2f(u0.x) + w1 * bf2f(u1.x);
        acc.y += w0 * bf2f(u0.y) + w1 * bf2f(u1.y);
        acc.z += w0 * bf2f(u0.z) + w1 * bf2f(u1.z);
        acc.w += w0 * bf2f(u0.w) + w1 * bf2f(u1.w);
    }
    ((float4*)red)[tid] = acc;
    __syncthreads();
    if (tid < 64) {
        float4 a = ((const float4*)red)[tid];
        float4 b4 = ((const float4*)red)[tid + 64];
        float4 c4 = ((const float4*)red)[tid + 128];
        float4 dd = ((const float4*)red)[tid + 192];
        float4 hres = ((const float4*)(Hres + (size_t)row * 256))[tid];
        float4 v;
        v.x = hres.x + a.x + b4.x + c4.x + dd.x;
        v.y = hres.y + a.y + b4.y + c4.y + dd.y;
        v.z = hres.z + a.z + b4.z + c4.z + dd.z;
        v.w = hres.w + a.w + b4.w + c4.w + dd.w;
        float s = v.x + v.y + v.z + v.w;
        float q = v.x * v.x + v.y * v.y + v.z * v.z + v.w * v.w;
        for (int o = 32; o; o >>= 1) { s += __shfl_xor(s, o); q += __shfl_xor(q, o); }
        float mu = s * (1.f / 256.f);
        float var = q * (1.f / 256.f) - mu * mu;
        if (var < 0.f) var = 0.f;
        float rs = rsqrtf(var + 1e-5f);
        float4 gg = ((const float4*)g)[tid];
        float4 bb = ((const float4*)bta)[tid];
        float4 o;
        o.x = (v.x - mu) * rs * gg.x + bb.x;
        o.y = (v.y - mu) * rs * gg.y + bb.y;
        o.z = (v.z - mu) * rs * gg.z + bb.z;
        o.w = (v.w - mu) * rs * gg.w + bb.w;
        ((float4*)(HLN + (size_t)row * 256))[tid] = o;
        ushort4 ob; ob.x = f2bf(o.x); ob.y = f2bf(o.y); ob.z = f2bf(o.z); ob.w = f2bf(o.w);
        ((ushort4*)(HLNb + (size_t)row * 256))[tid] = ob;
    }
}

// ---------------- bias+GELU on bf16 buffer (in-place) ----------------
__global__ void k_bias_gelu(unsigned short* __restrict__ M, const float* __restrict__ b1,
                            int n, int colmask) {
    int i = blockIdx.x * blockDim.x + threadIdx.x;
    if (i >= n) return;
    float x = bf2f(M[i]) + b1[i & colmask];
    float t = tanhf(0.7978845608028654f * (x + 0.044715f * x * x * x));
    M[i] = f2bf(0.5f * x * (1.f + t));
}

__global__ void k_final(const float* __restrict__ HLN, const float* __restrict__ FF,
                        const float* __restrict__ b2, float* __restrict__ out, int n) {
    int i = blockIdx.x * blockDim.x + threadIdx.x;
    if (i >= n) return;
    out[i] = HLN[i] + FF[i] + b2[i & 255];
}

extern "C" void kernel_launch(void* const* d_in, const int* in_sizes, int n_in,
                              void* d_out, int out_size, void* d_ws, size_t ws_size,
                              hipStream_t stream) {
    const float* adj   = (const float*)d_in[0];
    const float* x     = (const float*)d_in[1];
    const float* W0    = (const float*)d_in[2];
    const float* as0   = (const float*)d_in[3];
    const float* ad0   = (const float*)d_in[4];
    const float* W1    = (const float*)d_in[5];
    const float* as1   = (const float*)d_in[6];
    const float* ad1   = (const float*)d_in[7];
    const float* W2    = (const float*)d_in[8];
    const float* as2   = (const float*)d_in[9];
    const float* ad2   = (const float*)d_in[10];
    const float* ln_g  = (const float*)d_in[11];
    const float* ln_b  = (const float*)d_in[12];
    const float* ff_w1 = (const float*)d_in[13];
    const float* ff_b1 = (const float*)d_in[14];
    const float* ff_w2 = (const float*)d_in[15];
    const float* ff_b2 = (const float*)d_in[16];

    float* ws = (float*)d_ws;
    // fp32 buffers
    float* H    = ws;                         // [4096,256]
    float* HLN  = ws + 1048576;               // [4096,256]
    float* FF   = ws + 2097152;               // [4096,256]
    // bf16 buffers (sizes in float units = ushorts/2)
    unsigned short* Eb   = (unsigned short*)(ws + 3145728);   // [4096,2048] bf16 (4,194,304 fl)
    unsigned short* HPb  = (unsigned short*)(ws + 7340032);   // [4096,256]  (524,288 fl)
    unsigned short* xb   = (unsigned short*)(ws + 7864320);   // [4096,256]
    unsigned short* Hb   = (unsigned short*)(ws + 8388608);   // [4096,256]
    unsigned short* HLNb = (unsigned short*)(ws + 8912896);   // [4096,256]
    unsigned short* MIDb = (unsigned short*)(ws + 9437184);   // [4096,512]  (1,048,576 fl)
    unsigned short* W0t  = (unsigned short*)(ws + 10485760);  // [256,256]
    unsigned short* W1t  = (unsigned short*)(ws + 10518528);
    unsigned short* W2t  = (unsigned short*)(ws + 10551296);  // [2048,256]
    unsigned short* F1t  = (unsigned short*)(ws + 10813440);  // [512,256]
    unsigned short* F2t  = (unsigned short*)(ws + 10878976);  // [256,512]
    float* SRC = ws + 10944512;
    float* DST = ws + 10977280;
    int*   NBR = (int*)(ws + 11010048);
    int*   CNT = (int*)(ws + 11534336);

    k_csr<<<4096, 1024, 0, stream>>>(adj, NBR, CNT);
    k_cast4<<<1024, 256, 0, stream>>>(x, xb, 262144);
    k_castT<<<dim3(8, 8),  256, 0, stream>>>(W0, W0t, 256, 256);
    k_castT<<<dim3(8, 8),  256, 0, stream>>>(W1, W1t, 256, 256);
    k_castT<<<dim3(8, 64), 256, 0, stream>>>(W2, W2t, 256, 2048);
    k_castT<<<dim3(8, 16), 256, 0, stream>>>(ff_w1, F1t, 256, 512);
    k_castT<<<dim3(16, 8), 256, 0, stream>>>(ff_w2, F2t, 512, 256);

    // ---- GAT layer 0 ----
    k_gemm_mfma<<<dim3(4, 64), 256, 0, stream>>>(xb, W0t, HPb, 4096, 256, 256, 1);
    k_scores<<<8192, 256, 0, stream>>>(HPb, as0, ad0, SRC, DST, 32);
    k_attn_small_f<<<4096, 256, 0, stream>>>(HPb, SRC, DST, NBR, CNT, x, H, Hb);

    // ---- GAT layer 1 ----
    k_gemm_mfma<<<dim3(4, 64), 256, 0, stream>>>(Hb, W1t, HPb, 4096, 256, 256, 1);
    k_scores<<<8192, 256, 0, stream>>>(HPb, as1, ad1, SRC, DST, 32);
    k_attn_small_f<<<4096, 256, 0, stream>>>(HPb, SRC, DST, NBR, CNT, H, H, Hb);

    // ---- GAT layer 2 + head-mean + residual + LayerNorm ----
    k_gemm_mfma<<<dim3(32, 64), 256, 0, stream>>>(Hb, W2t, Eb, 4096, 2048, 256, 1);
    k_scores<<<8192, 256, 0, stream>>>(Eb, as2, ad2, SRC, DST, 256);
    k_attn_big_f<<<4096, 256, 0, stream>>>(Eb, SRC, DST, NBR, CNT, H, ln_g, ln_b, HLN, HLNb);

    // ---- FFN ----
    k_gemm_mfma<<<dim3(8, 64), 256, 0, stream>>>(HLNb, F1t, MIDb, 4096, 512, 256, 1);
    k_bias_gelu<<<8192, 256, 0, stream>>>(MIDb, ff_b1, 2097152, 511);
    k_gemm_mfma<<<dim3(4, 64), 256, 0, stream>>>(MIDb, F2t, FF, 4096, 256, 512, 0);
    k_final<<<4096, 256, 0, stream>>>(HLN, FF, ff_b2, (float*)d_out, 1048576);
}